// Round 3
// baseline (97.398 us; speedup 1.0000x reference)
//
#include <hip/hip_runtime.h>
#include <hip/hip_bf16.h>

// Fused attention: q = x1@Wq+bq, k = x2@Wk+bk, v = x2@Wv+bv (bf16, d padded 100->128),
// out = softmax(q k^T / 10) v. Flash-style, kv split 16-way + bf16-partial merge.
// ws: qg 2MB | kg 2MB | vT2 2MB (k-slot permuted) | pacc16 26MB (bf16) | pml 16*8192*float2

typedef __bf16 bf16x8 __attribute__((ext_vector_type(8)));
typedef float  f32x4  __attribute__((ext_vector_type(4)));
typedef short  short8_t __attribute__((ext_vector_type(8)));

#define SM_C 0.14426950408889634f   /* log2(e) / sqrt(100) */

#if __has_builtin(__builtin_amdgcn_global_load_lds)
#define HAVE_GLL 1
#endif

__device__ __forceinline__ void gload16(const short* g, short* l){
#ifdef HAVE_GLL
  __builtin_amdgcn_global_load_lds(
      (__attribute__((address_space(1))) void*)g,
      (__attribute__((address_space(3))) void*)l,
      16, 0, 0);
#else
  *(short8_t*)(l + (threadIdx.x & 63)*8) = *(const short8_t*)(g);
#endif
}

__device__ __forceinline__ short bf(float f){ return __builtin_bit_cast(short, (__bf16)f); }
__device__ __forceinline__ float bf2f(unsigned short v){
  unsigned u = ((unsigned)v) << 16;
  return __builtin_bit_cast(float, u);
}

// ---------------- projection kernel: 16 rows/block ----------------
__global__ __launch_bounds__(256) void proj_qkv(
    const float* __restrict__ x1, const float* __restrict__ x2,
    const float* __restrict__ Wq, const float* __restrict__ bq,
    const float* __restrict__ Wk, const float* __restrict__ bk,
    const float* __restrict__ Wv, const float* __restrict__ bv,
    short* __restrict__ qg, short* __restrict__ kg, short* __restrict__ vT2)
{
  __shared__ float xs[16][128];
  __shared__ float vs[16][104];
  const int z = blockIdx.y;
  const float* x = (z == 0) ? x1 : x2;
  const float* W = (z == 0) ? Wq : (z == 1) ? Wk : Wv;
  const float* b = (z == 0) ? bq : (z == 1) ? bk : bv;
  const int rb = blockIdx.x << 4;            // 16 rows per block
  const int t  = threadIdx.x;
  for (int i = t; i < 2048; i += 256) xs[i >> 7][i & 127] = x[(rb << 7) + i];
  __syncthreads();
  const int rw = t >> 5, cs = t & 31;        // rows rw, rw+8; cols cs*4..cs*4+3
  float4 a0 = make_float4(0.f,0.f,0.f,0.f), a1 = a0;
  if (cs < 25){
    a0 = *(const float4*)(b + (cs << 2)); a1 = a0;
#pragma unroll 8
    for (int i = 0; i < 128; ++i){
      const float4 wv = *(const float4*)(W + i*100 + (cs << 2));
      const float xv0 = xs[rw][i], xv1 = xs[rw+8][i];
      a0.x = fmaf(xv0, wv.x, a0.x); a0.y = fmaf(xv0, wv.y, a0.y);
      a0.z = fmaf(xv0, wv.z, a0.z); a0.w = fmaf(xv0, wv.w, a0.w);
      a1.x = fmaf(xv1, wv.x, a1.x); a1.y = fmaf(xv1, wv.y, a1.y);
      a1.z = fmaf(xv1, wv.z, a1.z); a1.w = fmaf(xv1, wv.w, a1.w);
    }
  }
  if (z < 2){
    short* o = (z == 0) ? qg : kg;
    if (cs < 25){
      short4 h0, h1;
      h0.x=bf(a0.x); h0.y=bf(a0.y); h0.z=bf(a0.z); h0.w=bf(a0.w);
      h1.x=bf(a1.x); h1.y=bf(a1.y); h1.z=bf(a1.z); h1.w=bf(a1.w);
      *(short4*)(o + ((rb + rw)     << 7) + (cs << 2)) = h0;
      *(short4*)(o + ((rb + rw + 8) << 7) + (cs << 2)) = h1;
    } else {
      short4 hz; hz.x=0; hz.y=0; hz.z=0; hz.w=0;   // zero-pad cols 100..127
      *(short4*)(o + ((rb + rw)     << 7) + 100 + ((cs - 25) << 2)) = hz;
      *(short4*)(o + ((rb + rw + 8) << 7) + 100 + ((cs - 25) << 2)) = hz;
    }
  } else {
    if (cs < 25){
      vs[rw  ][(cs<<2)+0]=a0.x; vs[rw  ][(cs<<2)+1]=a0.y; vs[rw  ][(cs<<2)+2]=a0.z; vs[rw  ][(cs<<2)+3]=a0.w;
      vs[rw+8][(cs<<2)+0]=a1.x; vs[rw+8][(cs<<2)+1]=a1.y; vs[rw+8][(cs<<2)+2]=a1.z; vs[rw+8][(cs<<2)+3]=a1.w;
    }
    __syncthreads();
    if (t < 128){
      const int d = t;
      // k-slot-permuted layout, 32-periodic: idx = g*8+j <-> kv = 4g + (j<4 ? j : 12+j)
#pragma unroll
      for (int h = 0; h < 4; ++h){
        const int kv0 = rb + h*4;
        const int o32 = kv0 & 31;
        const int idx = (o32 < 16) ? ((o32 >> 2) << 3) : ((((o32 - 16) >> 2) << 3) + 4);
        const int r0 = kv0 - rb;
        short4 hv;
        hv.x = (d<100)? bf(vs[r0+0][d]) : (short)0;
        hv.y = (d<100)? bf(vs[r0+1][d]) : (short)0;
        hv.z = (d<100)? bf(vs[r0+2][d]) : (short)0;
        hv.w = (d<100)? bf(vs[r0+3][d]) : (short)0;
        *(short4*)(vT2 + (d << 13) + (kv0 & ~31) + idx) = hv;
      }
    }
  }
}

// ---------------- flash attention: 1024 blocks = 64 qtiles x 16 parts, 4 waves ----------------
// KB=32 per tile; LDS ~34KB -> 4 blocks/CU.
__global__ __launch_bounds__(256, 4) void attn_fwd(
    const short* __restrict__ qg, const short* __restrict__ kg,
    const short* __restrict__ vT2, short* __restrict__ pacc,
    float2* __restrict__ pml)
{
  __shared__ alignas(1024) short sK[2][32*128];   // 8KB/buf, 16B-block swizzled (XOR r&15)
  __shared__ alignas(1024) short sVT[2][4608];    // 9216B/buf: 112 rows x 80B stride
  const int tid  = threadIdx.x;
  const int w    = tid >> 6;
  const int lane = tid & 63;
  const int g    = lane >> 4;
  const int ln   = lane & 15;
  const int qt   = blockIdx.x & 63;
  const int part = blockIdx.x >> 6;
  const int qb   = qt*128 + w*32;

  // Q fragments: lane holds Q[qb+sub*16+ln][ks*32 + g*8 + j]
  bf16x8 qf[2][4];
#pragma unroll
  for (int sub = 0; sub < 2; ++sub)
#pragma unroll
    for (int ks = 0; ks < 4; ++ks)
      qf[sub][ks] = *(const bf16x8*)(qg + (qb + sub*16 + ln)*128 + ks*32 + g*8);

  f32x4 acc[2][7];
#pragma unroll
  for (int sub = 0; sub < 2; ++sub)
#pragma unroll
    for (int db = 0; db < 7; ++db) acc[sub][db] = f32x4{0.f,0.f,0.f,0.f};
  float mrun[2] = {-3.0e38f, -3.0e38f};
  float lsum[2] = {0.f, 0.f};

  auto stage = [&](int kv0, int buf){
#pragma unroll
    for (int i = 0; i < 2; ++i){              // K: 8 x 1KB chunks
      const int cid = w + (i << 2);
      const int r   = (cid << 2) + (lane >> 4);
      const int bx  = (lane & 15) ^ (r & 15);
      gload16(kg + (kv0 + r)*128 + bx*8, &sK[buf][cid << 9]);
    }
#pragma unroll
    for (int i = 0; i < 3; ++i){              // VT: 9 x 1KB chunks, 80B row stride
      const int cid = w + (i << 2);
      if (cid < 9){
        const int a = (cid << 10) + (lane << 4);   // dest byte (incl lane)
        const int r = a / 80;                      // VT row (d)
        const int m = (a - r*80) >> 4;             // 16B slot 0..4 (4 = pad)
        const int srcm = (m == 4) ? 0 : m;
        gload16(vT2 + r*8192 + kv0 + srcm*8, &sVT[buf][cid << 9]);
      }
    }
  };

  const int kvbase = part << 9;               // 512 kv per part
  stage(kvbase, 0);
  int cur = 0;
  for (int t = 0; t < 16; ++t){
    __syncthreads();                          // staging of buf[cur] complete
    if (t < 15) stage(kvbase + ((t+1) << 5), cur ^ 1);
    const short* sKc = sK[cur];
    const short* sVc = sVT[cur];

    // ---- QK^T (swapped): st[sub][s][r] = score[kv=16s+4g+r][q=qb+sub*16+ln] ----
    f32x4 st[2][2];
#pragma unroll
    for (int s = 0; s < 2; ++s){ st[0][s] = f32x4{0.f,0.f,0.f,0.f}; st[1][s] = f32x4{0.f,0.f,0.f,0.f}; }
    __builtin_amdgcn_s_setprio(1);
#pragma unroll
    for (int s = 0; s < 2; ++s){
      const int rbase = (s*16 + ln) << 7;
#pragma unroll
      for (int ks = 0; ks < 4; ++ks){
        bf16x8 kf = *(const bf16x8*)(sKc + rbase + ((((ks<<2) + g) ^ ln) << 3));
        st[0][s] = __builtin_amdgcn_mfma_f32_16x16x32_bf16(kf, qf[0][ks], st[0][s], 0, 0, 0);
        st[1][s] = __builtin_amdgcn_mfma_f32_16x16x32_bf16(kf, qf[1][ks], st[1][s], 0, 0, 0);
      }
    }
    __builtin_amdgcn_s_setprio(0);

    // ---- online softmax with defer-max (THR = 8 score units -> P <= e^0.8) ----
    bf16x8 pb[2];
#pragma unroll
    for (int sub = 0; sub < 2; ++sub){
      float mx = st[sub][0][0];
#pragma unroll
      for (int s = 0; s < 2; ++s)
#pragma unroll
        for (int r = 0; r < 4; ++r) mx = fmaxf(mx, st[sub][s][r]);
      mx = fmaxf(mx, __shfl_xor(mx, 16));
      mx = fmaxf(mx, __shfl_xor(mx, 32));
      if (!__all(mx - mrun[sub] <= 8.0f)){
        const float mnew = fmaxf(mrun[sub], mx);
        const float f = exp2f((mrun[sub] - mnew) * SM_C);
        lsum[sub] *= f;
#pragma unroll
        for (int db = 0; db < 7; ++db) acc[sub][db] *= f;
        mrun[sub] = mnew;
      }
      const float mc = mrun[sub] * SM_C;
      float p[2][4]; float ps = 0.f;
#pragma unroll
      for (int s = 0; s < 2; ++s)
#pragma unroll
        for (int r = 0; r < 4; ++r){
          p[s][r] = exp2f(fmaf(st[sub][s][r], SM_C, -mc));
          ps += p[s][r];
        }
      lsum[sub] += ps;
      bf16x8 pv;
#pragma unroll
      for (int r = 0; r < 4; ++r){
        pv[r]   = (__bf16)p[0][r];       // k-slot j<4  -> kv = 4g+j
        pv[4+r] = (__bf16)p[1][r];       // k-slot j>=4 -> kv = 16+4g+(j-4)
      }
      pb[sub] = pv;
    }

    // ---- PV: out^T += V^T x P^T; one b128 A-frag per db (80B-stride rows) ----
    __builtin_amdgcn_s_setprio(1);
#pragma unroll
    for (int db = 0; db < 7; ++db){
      const int row = db*16 + ln;
      bf16x8 vf = *(const bf16x8*)(sVc + row*40 + (g << 3));
      acc[0][db] = __builtin_amdgcn_mfma_f32_16x16x32_bf16(vf, pb[0], acc[0][db], 0, 0, 0);
      acc[1][db] = __builtin_amdgcn_mfma_f32_16x16x32_bf16(vf, pb[1], acc[1][db], 0, 0, 0);
    }
    __builtin_amdgcn_s_setprio(0);
    cur ^= 1;
  }

  // ---- epilogue: finish row sums, write bf16 partials ----
#pragma unroll
  for (int sub = 0; sub < 2; ++sub){
    float ls = lsum[sub];
    ls += __shfl_xor(ls, 16);
    ls += __shfl_xor(ls, 32);
    lsum[sub] = ls;
  }
#pragma unroll
  for (int sub = 0; sub < 2; ++sub)
#pragma unroll
    for (int db = 0; db < 7; ++db)
#pragma unroll
      for (int r = 0; r < 4; ++r){
        const int d = db*16 + g*4 + r;
        if (d < 100)
          pacc[((part*100 + d) << 13) + qb + sub*16 + ln] = bf(acc[sub][db][r]);
      }
  if (g == 0) pml[(part << 13) + qb + ln]      = make_float2(mrun[0], lsum[0]);
  if (g == 1) pml[(part << 13) + qb + 16 + ln] = make_float2(mrun[1], lsum[1]);
}

// ---------------- merge kernel: 128 qblocks x 5 d-chunks, 16 parts ----------------
__global__ __launch_bounds__(256) void merge_parts(
    const short* __restrict__ pacc, const float2* __restrict__ pml,
    float* __restrict__ out)
{
  __shared__ float ol[64][21];
  const int t  = threadIdx.x;
  const int tq = t & 63;
  const int td = t >> 6;                 // 0..3 (wave-uniform)
  const int qb = blockIdx.x << 6;
  const int db = blockIdx.y * 20;
  const int q  = qb + tq;
  float m16[16], l16[16];
  float mstar = -3.0e38f;
#pragma unroll
  for (int p = 0; p < 16; ++p){
    float2 ml = pml[(p << 13) + q];
    m16[p] = ml.x; l16[p] = ml.y;
    mstar = fmaxf(mstar, ml.x);
  }
  float L = 0.f; float w16[16];
#pragma unroll
  for (int p = 0; p < 16; ++p){ w16[p] = exp2f((m16[p] - mstar) * SM_C); L += l16[p]*w16[p]; }
  const float inv = 1.0f / L;
#pragma unroll
  for (int i = 0; i < 5; ++i){
    const int d = db + td*5 + i;
    float s = 0.f;
#pragma unroll
    for (int p = 0; p < 16; ++p)
      s += bf2f((unsigned short)pacc[((p*100 + d) << 13) + q]) * w16[p];
    ol[tq][td*5 + i] = s * inv;
  }
  __syncthreads();
  for (int idx = t; idx < 1280; idx += 256){
    const int q2 = idx / 20, d2 = idx - q2*20;
    out[(qb + q2)*100 + db + d2] = ol[q2][d2];
  }
}

// ---------------- launcher ----------------
extern "C" void kernel_launch(void* const* d_in, const int* in_sizes, int n_in,
                              void* d_out, int out_size, void* d_ws, size_t ws_size,
                              hipStream_t stream)
{
  const float* x1 = (const float*)d_in[0];
  const float* x2 = (const float*)d_in[1];
  const float* Wq = (const float*)d_in[2];
  const float* bq = (const float*)d_in[3];
  const float* Wk = (const float*)d_in[4];
  const float* bk = (const float*)d_in[5];
  const float* Wv = (const float*)d_in[6];
  const float* bv = (const float*)d_in[7];
  char* ws = (char*)d_ws;
  short*  qg   = (short*)ws;                                  // 2 MB
  short*  kg   = (short*)(ws + (1u << 21));                   // 2 MB
  short*  vT2  = (short*)(ws + (2u << 21));                   // 2 MB (k-slot permuted)
  short*  pacc = (short*)(ws + (3u << 21));                   // 16*100*8192*2 B = 26.2 MB
  float2* pml  = (float2*)(ws + (3u << 21) + 16u*100u*8192u*2u);  // 1 MB
  float*  out  = (float*)d_out;

  proj_qkv<<<dim3(512, 3), 256, 0, stream>>>(x1, x2, Wq, bq, Wk, bk, Wv, bv, qg, kg, vT2);
  attn_fwd<<<1024, 256, 0, stream>>>(qg, kg, vT2, pacc, pml);
  merge_parts<<<dim3(128, 5), 256, 0, stream>>>(pacc, pml, out);
}

// Round 4
// 89.430 us; speedup vs baseline: 1.0891x; 1.0891x over previous
//
#include <hip/hip_runtime.h>
#include <hip/hip_bf16.h>

// Fused attention: q = x1@Wq+bq, k = x2@Wk+bk, v = x2@Wv+bv (bf16, d padded 100->128),
// out = softmax(q k^T / 10) v. Flash-style with STATIC per-row max bound
// m_est[q] = ||q||*max||k|| (Cauchy-Schwarz, computed on rounded bf16 values) ->
// no online-max, no rescale; row-sum via ones-column (d=100) in the PV MFMA.
// kv split 16-way; merge = plain sums (exact).
// ws: qg 2MB | kg 2MB | vT2 2MB (k-slot permuted) | pacc bf16 26.2MB | lsumg 512KB | q2g 32KB | Mk2 4B

typedef __bf16 bf16x8 __attribute__((ext_vector_type(8)));
typedef float  f32x4  __attribute__((ext_vector_type(4)));
typedef short  short8_t __attribute__((ext_vector_type(8)));

#define SM_C 0.14426950408889634f   /* log2(e) / sqrt(100) */

#if __has_builtin(__builtin_amdgcn_global_load_lds)
#define HAVE_GLL 1
#endif

__device__ __forceinline__ void gload16(const short* g, short* l){
#ifdef HAVE_GLL
  __builtin_amdgcn_global_load_lds(
      (__attribute__((address_space(1))) void*)g,
      (__attribute__((address_space(3))) void*)l,
      16, 0, 0);
#else
  *(short8_t*)(l + (threadIdx.x & 63)*8) = *(const short8_t*)(g);
#endif
}

__device__ __forceinline__ short bf(float f){ return __builtin_bit_cast(short, (__bf16)f); }
__device__ __forceinline__ float bf2f(unsigned short v){
  unsigned u = ((unsigned)v) << 16;
  return __builtin_bit_cast(float, u);
}

// ---------------- projection kernel: 16 rows/block; also emits ||q||^2, max||k||^2 ----------------
__global__ __launch_bounds__(256) void proj_qkv(
    const float* __restrict__ x1, const float* __restrict__ x2,
    const float* __restrict__ Wq, const float* __restrict__ bq,
    const float* __restrict__ Wk, const float* __restrict__ bk,
    const float* __restrict__ Wv, const float* __restrict__ bv,
    short* __restrict__ qg, short* __restrict__ kg, short* __restrict__ vT2,
    float* __restrict__ q2g, unsigned* __restrict__ Mk2)
{
  __shared__ float xs[16][128];
  __shared__ float vs[16][104];
  __shared__ float kred[8];
  const int z = blockIdx.y;
  const float* x = (z == 0) ? x1 : x2;
  const float* W = (z == 0) ? Wq : (z == 1) ? Wk : Wv;
  const float* b = (z == 0) ? bq : (z == 1) ? bk : bv;
  const int rb = blockIdx.x << 4;            // 16 rows per block
  const int t  = threadIdx.x;
  for (int i = t; i < 2048; i += 256) xs[i >> 7][i & 127] = x[(rb << 7) + i];
  __syncthreads();
  const int rw = t >> 5, cs = t & 31;        // rows rw, rw+8; cols cs*4..cs*4+3
  float4 a0 = make_float4(0.f,0.f,0.f,0.f), a1 = a0;
  if (cs < 25){
    a0 = *(const float4*)(b + (cs << 2)); a1 = a0;
#pragma unroll 8
    for (int i = 0; i < 128; ++i){
      const float4 wv = *(const float4*)(W + i*100 + (cs << 2));
      const float xv0 = xs[rw][i], xv1 = xs[rw+8][i];
      a0.x = fmaf(xv0, wv.x, a0.x); a0.y = fmaf(xv0, wv.y, a0.y);
      a0.z = fmaf(xv0, wv.z, a0.z); a0.w = fmaf(xv0, wv.w, a0.w);
      a1.x = fmaf(xv1, wv.x, a1.x); a1.y = fmaf(xv1, wv.y, a1.y);
      a1.z = fmaf(xv1, wv.z, a1.z); a1.w = fmaf(xv1, wv.w, a1.w);
    }
  }
  if (z < 2){
    short* o = (z == 0) ? qg : kg;
    float sq0 = 0.f, sq1 = 0.f;
    if (cs < 25){
      short4 h0, h1;
      h0.x=bf(a0.x); h0.y=bf(a0.y); h0.z=bf(a0.z); h0.w=bf(a0.w);
      h1.x=bf(a1.x); h1.y=bf(a1.y); h1.z=bf(a1.z); h1.w=bf(a1.w);
      *(short4*)(o + ((rb + rw)     << 7) + (cs << 2)) = h0;
      *(short4*)(o + ((rb + rw + 8) << 7) + (cs << 2)) = h1;
      // squared norms of the ROUNDED values (so the bound covers the MFMA inputs)
      float r0x=bf2f((unsigned short)h0.x), r0y=bf2f((unsigned short)h0.y),
            r0z=bf2f((unsigned short)h0.z), r0w=bf2f((unsigned short)h0.w);
      float r1x=bf2f((unsigned short)h1.x), r1y=bf2f((unsigned short)h1.y),
            r1z=bf2f((unsigned short)h1.z), r1w=bf2f((unsigned short)h1.w);
      sq0 = r0x*r0x + r0y*r0y + r0z*r0z + r0w*r0w;
      sq1 = r1x*r1x + r1y*r1y + r1z*r1z + r1w*r1w;
    } else {
      short4 hz; hz.x=0; hz.y=0; hz.z=0; hz.w=0;   // zero-pad cols 100..127
      *(short4*)(o + ((rb + rw)     << 7) + 100 + ((cs - 25) << 2)) = hz;
      *(short4*)(o + ((rb + rw + 8) << 7) + 100 + ((cs - 25) << 2)) = hz;
    }
#pragma unroll
    for (int s2 = 1; s2 < 32; s2 <<= 1){
      sq0 += __shfl_xor(sq0, s2, 32);
      sq1 += __shfl_xor(sq1, s2, 32);
    }
    if (z == 0){
      if (cs == 0){ q2g[rb + rw] = sq0; q2g[rb + rw + 8] = sq1; }
    } else {
      if (cs == 0) kred[rw] = fmaxf(sq0, sq1);
      __syncthreads();
      if (t == 0){
        float m = kred[0];
#pragma unroll
        for (int j = 1; j < 8; ++j) m = fmaxf(m, kred[j]);
        atomicMax(Mk2, __float_as_uint(m));
      }
    }
  } else {
    if (cs < 25){
      vs[rw  ][(cs<<2)+0]=a0.x; vs[rw  ][(cs<<2)+1]=a0.y; vs[rw  ][(cs<<2)+2]=a0.z; vs[rw  ][(cs<<2)+3]=a0.w;
      vs[rw+8][(cs<<2)+0]=a1.x; vs[rw+8][(cs<<2)+1]=a1.y; vs[rw+8][(cs<<2)+2]=a1.z; vs[rw+8][(cs<<2)+3]=a1.w;
    }
    __syncthreads();
    if (t < 128){
      const int d = t;
      // k-slot-permuted layout, 32-periodic: idx = g*8+j <-> kv = 4g + (j<4 ? j : 12+j)
      // d==100 -> ones column (row-sum extraction); d>100 -> zeros
#pragma unroll
      for (int h = 0; h < 4; ++h){
        const int kv0 = rb + h*4;
        const int o32 = kv0 & 31;
        const int idx = (o32 < 16) ? ((o32 >> 2) << 3) : ((((o32 - 16) >> 2) << 3) + 4);
        const int r0 = kv0 - rb;
        short4 hv;
        hv.x = (d<100)? bf(vs[r0+0][d]) : (d==100 ? (short)0x3F80 : (short)0);
        hv.y = (d<100)? bf(vs[r0+1][d]) : (d==100 ? (short)0x3F80 : (short)0);
        hv.z = (d<100)? bf(vs[r0+2][d]) : (d==100 ? (short)0x3F80 : (short)0);
        hv.w = (d<100)? bf(vs[r0+3][d]) : (d==100 ? (short)0x3F80 : (short)0);
        *(short4*)(vT2 + (d << 13) + (kv0 & ~31) + idx) = hv;
      }
    }
  }
}

// ---------------- flash attention: 1024 blocks = 64 qtiles x 16 parts (XCD-swizzled) ----------------
// 4 waves x 32 q rows; KB=32; LDS 30KB -> 4 blocks/CU.
__global__ __launch_bounds__(256, 4) void attn_fwd(
    const short* __restrict__ qg, const short* __restrict__ kg,
    const short* __restrict__ vT2, const float* __restrict__ q2g,
    const unsigned* __restrict__ Mk2, short* __restrict__ pacc,
    float* __restrict__ lsumg)
{
  __shared__ alignas(1024) short sK[2][4096];    // 8KB/buf, 16B-block swizzled (XOR r&15)
  __shared__ alignas(1024) short sVT[2][3584];   // 7KB/buf: 56 super-rows (2 d's) x 128B, XOR dd&3
  const int tid  = threadIdx.x;
  const int w    = tid >> 6;
  const int lane = tid & 63;
  const int g    = lane >> 4;
  const int ln   = lane & 15;
  // XCD swizzle: 2 consecutive parts per XCD -> K/V L2-resident per XCD
  const int orig = blockIdx.x;
  const int part = ((orig & 7) << 1) | ((orig >> 3) & 1);
  const int qt   = orig >> 4;
  const int qb   = qt*128 + w*32;

  // static row-max bound: m_est = ||q|| * max||k|| (>= any score by Cauchy-Schwarz)
  const float mk2 = __uint_as_float(*Mk2);
  float negmc[2];
#pragma unroll
  for (int sub = 0; sub < 2; ++sub){
    const float q2 = q2g[qb + sub*16 + ln];
    negmc[sub] = -sqrtf(q2 * mk2) * 1.0009f * SM_C;
  }

  // Q fragments: lane holds Q[qb+sub*16+ln][ks*32 + g*8 + j]
  bf16x8 qf[2][4];
#pragma unroll
  for (int sub = 0; sub < 2; ++sub)
#pragma unroll
    for (int ks = 0; ks < 4; ++ks)
      qf[sub][ks] = *(const bf16x8*)(qg + (qb + sub*16 + ln)*128 + ks*32 + g*8);

  f32x4 acc[2][7];
#pragma unroll
  for (int sub = 0; sub < 2; ++sub)
#pragma unroll
    for (int db = 0; db < 7; ++db) acc[sub][db] = f32x4{0.f,0.f,0.f,0.f};

  // per-lane source bases for staging (advance by kv offset per tile)
  const short* kbase[2];
  const short* vbase[2];
  int vok[2];
#pragma unroll
  for (int i = 0; i < 2; ++i){
    const int cid = w + (i << 2);
    { const int r  = (cid << 2) + (lane >> 4);
      const int bx = (lane & 15) ^ (r & 15);
      kbase[i] = kg + r*128 + bx*8; }
    { const int a  = (cid << 10) + (lane << 4);  // dest byte
      const int dd = a >> 7, hh = (a >> 6) & 1, bb = (a >> 4) & 3;
      const int d  = (dd << 1) + hh;
      const int gs = bb ^ (dd & 3);
      vbase[i] = vT2 + d*8192 + gs*8;
      vok[i] = (cid < 7); }
  }

  auto stage = [&](int kv0, int buf){
#pragma unroll
    for (int i = 0; i < 2; ++i)
      gload16(kbase[i] + kv0*128, &sK[buf][(w + (i << 2)) << 9]);
#pragma unroll
    for (int i = 0; i < 2; ++i)
      if (vok[i]) gload16(vbase[i] + kv0, &sVT[buf][(w + (i << 2)) << 9]);
  };

  const int kvbase = part << 9;               // 512 kv per part
  stage(kvbase, 0);
  int cur = 0;
  for (int t = 0; t < 16; ++t){
    __syncthreads();                          // staging of buf[cur] complete
    if (t < 15) stage(kvbase + ((t+1) << 5), cur ^ 1);
    const short* sKc = sK[cur];
    const short* sVc = sVT[cur];

    // ---- QK^T (swapped): st[sub][s][r] = score_st[kv=16s+4g+r][q=qb+sub*16+ln] ----
    f32x4 st[2][2];
#pragma unroll
    for (int s = 0; s < 2; ++s){ st[0][s] = f32x4{0.f,0.f,0.f,0.f}; st[1][s] = f32x4{0.f,0.f,0.f,0.f}; }
    __builtin_amdgcn_s_setprio(1);
#pragma unroll
    for (int s = 0; s < 2; ++s){
      const int rbase = (s*16 + ln) << 7;
#pragma unroll
      for (int ks = 0; ks < 4; ++ks){
        bf16x8 kf = *(const bf16x8*)(sKc + rbase + ((((ks<<2) + g) ^ ln) << 3));
        st[0][s] = __builtin_amdgcn_mfma_f32_16x16x32_bf16(kf, qf[0][ks], st[0][s], 0, 0, 0);
        st[1][s] = __builtin_amdgcn_mfma_f32_16x16x32_bf16(kf, qf[1][ks], st[1][s], 0, 0, 0);
      }
    }
    __builtin_amdgcn_s_setprio(0);

    // ---- softmax numerator: p = exp2(st*C - m_est*C); no max, no rescale, no sum ----
    bf16x8 pb[2];
#pragma unroll
    for (int sub = 0; sub < 2; ++sub){
      bf16x8 pv;
#pragma unroll
      for (int r = 0; r < 4; ++r){
        pv[r]   = (__bf16)exp2f(fmaf(st[sub][0][r], SM_C, negmc[sub]));  // k-slot j<4  -> kv=4g+j
        pv[4+r] = (__bf16)exp2f(fmaf(st[sub][1][r], SM_C, negmc[sub]));  // k-slot j>=4 -> kv=16+4g+(j-4)
      }
      pb[sub] = pv;
    }

    // ---- PV: out^T += V^T x P^T (ones-column at d=100 yields row sums) ----
    __builtin_amdgcn_s_setprio(1);
#pragma unroll
    for (int db = 0; db < 7; ++db){
      const int row = db*16 + ln;
      const int dd  = row >> 1;
      bf16x8 vf = *(const bf16x8*)(sVc + (dd << 6) + ((row & 1) << 5) + ((g ^ (dd & 3)) << 3));
      acc[0][db] = __builtin_amdgcn_mfma_f32_16x16x32_bf16(vf, pb[0], acc[0][db], 0, 0, 0);
      acc[1][db] = __builtin_amdgcn_mfma_f32_16x16x32_bf16(vf, pb[1], acc[1][db], 0, 0, 0);
    }
    __builtin_amdgcn_s_setprio(0);
    cur ^= 1;
  }

  // ---- epilogue: bf16 partials (d<100) + fp32 row-sums from the ones-column (d=100) ----
#pragma unroll
  for (int sub = 0; sub < 2; ++sub){
#pragma unroll
    for (int db = 0; db < 7; ++db)
#pragma unroll
      for (int r = 0; r < 4; ++r){
        const int d = db*16 + g*4 + r;
        if (d < 100)
          pacc[((part*100 + d) << 13) + qb + sub*16 + ln] = bf(acc[sub][db][r]);
      }
    if (g == 1)  // acc[sub][6][0] is d=96+4*1+0 = 100 -> lsum for this q row
      lsumg[(part << 13) + qb + sub*16 + ln] = acc[sub][6][0];
  }
}

// ---------------- merge kernel: exp-free exact merge (common m_est cancels) ----------------
__global__ __launch_bounds__(256) void merge_parts(
    const short* __restrict__ pacc, const float* __restrict__ lsumg,
    float* __restrict__ out)
{
  __shared__ float ol[64][21];
  const int t  = threadIdx.x;
  const int tq = t & 63;
  const int td = t >> 6;                 // 0..3 (wave-uniform)
  const int qb = blockIdx.x << 6;
  const int db = blockIdx.y * 20;
  const int q  = qb + tq;
  float L = 0.f;
#pragma unroll
  for (int p = 0; p < 16; ++p) L += lsumg[(p << 13) + q];
  const float inv = 1.0f / L;
#pragma unroll
  for (int i = 0; i < 5; ++i){
    const int d = db + td*5 + i;
    float s = 0.f;
#pragma unroll
    for (int p = 0; p < 16; ++p)
      s += bf2f((unsigned short)pacc[((p*100 + d) << 13) + q]);
    ol[tq][td*5 + i] = s * inv;
  }
  __syncthreads();
  for (int idx = t; idx < 1280; idx += 256){
    const int q2 = idx / 20, d2 = idx - q2*20;
    out[(qb + q2)*100 + db + d2] = ol[q2][d2];
  }
}

// ---------------- launcher ----------------
extern "C" void kernel_launch(void* const* d_in, const int* in_sizes, int n_in,
                              void* d_out, int out_size, void* d_ws, size_t ws_size,
                              hipStream_t stream)
{
  const float* x1 = (const float*)d_in[0];
  const float* x2 = (const float*)d_in[1];
  const float* Wq = (const float*)d_in[2];
  const float* bq = (const float*)d_in[3];
  const float* Wk = (const float*)d_in[4];
  const float* bk = (const float*)d_in[5];
  const float* Wv = (const float*)d_in[6];
  const float* bv = (const float*)d_in[7];
  char* ws = (char*)d_ws;
  short*    qg    = (short*)ws;                                   // 2 MB
  short*    kg    = (short*)(ws + (1u << 21));                    // 2 MB
  short*    vT2   = (short*)(ws + (2u << 21));                    // 2 MB (k-slot permuted)
  short*    pacc  = (short*)(ws + (3u << 21));                    // 16*100*8192*2 = 26.2 MB
  float*    lsumg = (float*)(ws + (3u << 21) + 26214400u);        // 16*8192*4 = 512 KB
  float*    q2g   = (float*)(ws + (3u << 21) + 26214400u + 524288u);  // 32 KB
  unsigned* Mk2   = (unsigned*)(ws + (3u << 21) + 26214400u + 524288u + 32768u);
  float*    out   = (float*)d_out;

  hipMemsetAsync(Mk2, 0, 4, stream);
  proj_qkv<<<dim3(512, 3), 256, 0, stream>>>(x1, x2, Wq, bq, Wk, bk, Wv, bv,
                                             qg, kg, vT2, q2g, Mk2);
  attn_fwd<<<1024, 256, 0, stream>>>(qg, kg, vT2, q2g, Mk2, pacc, lsumg);
  merge_parts<<<dim3(128, 5), 256, 0, stream>>>(pacc, lsumg, out);
}